// Round 16
// baseline (252.384 us; speedup 1.0000x reference)
//
#include <hip/hip_runtime.h>

// ---------------------------------------------------------------------------
// MultiQueryAttention: out = softmax_causal((xWq+bq)(xWk+bk)^T * scale) (xWv+bv) Wo + bo
// B=2, S=2048, HIDDEN=2048, HEADS=16 (multi-query: 1 KV head), HEAD_DIM=128
// R15: attn -> V read DIRECTLY from global (L2-resident, PV-permuted ->
//      contiguous 16B/lane); V LDS staging + V LDS reads deleted (halves the
//      LDS-BW bind, occupancy-neutral). K staging unchanged. LDS 32KB.
//      GEMMs unchanged (R14: qkv BK=32, out BK=64).
// ---------------------------------------------------------------------------

#define HIDDEN 2048
#define NHEADS 16
#define HDIM 128
#define BATCH 2
#define SEQ 2048
// SCALE_QK * log2(e): softmax computed in base-2 (exp2); folded into Wq/bq.
#define SCALE_L2E 0.1275258653864023f

typedef __attribute__((ext_vector_type(8))) short bfrag;   // 8 bf16 (4 VGPRs)
typedef __attribute__((ext_vector_type(4))) float facc;    // MFMA accumulator
typedef __attribute__((ext_vector_type(4))) unsigned int uifrag;  // 4 u32 = 8 bf16

__device__ __forceinline__ unsigned short f2bf(float f) {  // f32 -> bf16 RNE
  unsigned int u = __float_as_uint(f);
  u += 0x7fffu + ((u >> 16) & 1u);
  return (unsigned short)(u >> 16);
}

// HW packed f32x2 -> bf16x2 (RNE); no builtin on gfx950, inline asm (T12).
__device__ __forceinline__ unsigned int cvt_pk_bf16(float lo, float hi) {
  unsigned int r;
  asm("v_cvt_pk_bf16_f32 %0, %1, %2" : "=v"(r) : "v"(lo), "v"(hi));
  return r;
}

// async global->LDS, 16B per lane. LDS dest is WAVE-UNIFORM base (+lane*16 by HW).
__device__ __forceinline__ void gl_lds16(const void* g, void* l) {
  __builtin_amdgcn_global_load_lds(
      (const __attribute__((address_space(1))) void*)g,
      (__attribute__((address_space(3))) void*)l, 16, 0, 0);
}

#define SBAR() __builtin_amdgcn_s_barrier()
#define CFENCE() asm volatile("" ::: "memory")
#define WAIT_VM(n) asm volatile("s_waitcnt vmcnt(" #n ")" ::: "memory")

// ---------------------------------------------------------------------------
// x f32 -> bf16 (vectorized, HW cvt_pk)
__global__ __launch_bounds__(256) void cvt_bf16(const float* __restrict__ in,
                                                unsigned int* __restrict__ out, int n4) {
  int i = blockIdx.x * 256 + threadIdx.x;
  if (i >= n4) return;
  float4 v = ((const float4*)in)[i];
  uint2 o = {cvt_pk_bf16(v.x, v.y), cvt_pk_bf16(v.z, v.w)};
  ((uint2*)out)[i] = o;
}

// Two weights per launch (blockIdx.z picks): W [K][N] f32 -> WT [N][K] bf16,
// scaled by s0/s1 (used to fold the softmax scale into Wq).
__global__ __launch_bounds__(256) void transpose_cvt2(const float* __restrict__ W0,
                                                      short* __restrict__ T0,
                                                      const float* __restrict__ W1,
                                                      short* __restrict__ T1,
                                                      int K, int N,
                                                      float s0, float s1) {
  const float* W = blockIdx.z ? W1 : W0;
  short* WT = blockIdx.z ? T1 : T0;
  const float s = blockIdx.z ? s1 : s0;
  __shared__ float t[32][33];
  int tx = threadIdx.x & 31, ty = threadIdx.x >> 5;
  int n0 = blockIdx.x * 32, k0 = blockIdx.y * 32;
#pragma unroll
  for (int j = 0; j < 4; ++j)
    t[ty + j * 8][tx] = W[(size_t)(k0 + ty + j * 8) * N + n0 + tx];
  __syncthreads();
#pragma unroll
  for (int j = 0; j < 4; ++j)
    WT[(size_t)(n0 + ty + j * 8) * K + k0 + tx] = (short)f2bf(t[tx][ty + j * 8] * s);
}

// PV-order permutation of a key index within its 64-block:
// key bits [c][h][g1g0][r1r0] -> pos bits [c][g1g0][h][r1r0].
__device__ __forceinline__ int pv_perm64(int row) {
  int k = row & 63;
  int p = (k & 0x23) | ((k & 0x0C) << 1) | ((k & 0x10) >> 2);
  return (row & ~63) | p;
}

// ---------------------------------------------------------------------------
// gemm_qkv: BK=32 pipeline. 512 threads = 8 waves (4M x 2N), per-wave C 32x64.
// LDS 32KB -> 3 blocks/CU; grid 576 fully resident. Grid (32, 18).
__global__ __launch_bounds__(512, 6) void gemm_qkv(const short* __restrict__ A,
                                                   const short* __restrict__ BT,
                                                   const float* __restrict__ bq,
                                                   const float* __restrict__ bk,
                                                   const float* __restrict__ bv,
                                                   unsigned short* __restrict__ Qb,
                                                   unsigned short* __restrict__ Kb,
                                                   unsigned short* __restrict__ Vtb,
                                                   int M, int K) {
  __shared__ __align__(16) short Al[2][128 * 32];
  __shared__ __align__(16) short Bl[2][128 * 32];
  const int tid = threadIdx.x;
  const int w = tid >> 6, l = tid & 63;
  const int wm = w >> 1, wn = w & 1;
  const int l15 = l & 15, l4 = l >> 4;
  const int m0 = blockIdx.x * 128, n0 = blockIdx.y * 128;

  const short *ap, *bp;
  {
    int C = w * 64 + l;
    int row = C >> 2, c = C & 3;
    int sz = (c ^ (row & 3)) << 3;
    ap = A + (size_t)(m0 + row) * K + sz;
    bp = BT + (size_t)(n0 + row) * K + sz;
  }
  int aoffs[2], boffs[4];
#pragma unroll
  for (int mt = 0; mt < 2; ++mt) {
    int row = wm * 32 + mt * 16 + l15;
    aoffs[mt] = row * 64 + ((l4 ^ (row & 3)) << 4);
  }
#pragma unroll
  for (int nt = 0; nt < 4; ++nt) {
    int row = wn * 64 + nt * 16 + l15;
    boffs[nt] = row * 64 + ((l4 ^ (row & 3)) << 4);
  }

  facc acc[2][4] = {};
  const int nkt = K >> 5;  // 64
  gl_lds16(ap, &Al[0][w * 512]);
  gl_lds16(bp, &Bl[0][w * 512]);
  for (int kt = 0; kt < nkt; ++kt) {
    const int cur = kt & 1;
    if (kt + 1 < nkt) {
      gl_lds16(ap + (kt + 1) * 32, &Al[cur ^ 1][w * 512]);
      gl_lds16(bp + (kt + 1) * 32, &Bl[cur ^ 1][w * 512]);
      WAIT_VM(2);
    } else {
      WAIT_VM(0);
    }
    SBAR();
    CFENCE();
    const char* AlB = (const char*)Al + (cur << 13);
    const char* BlB = (const char*)Bl + (cur << 13);
    __builtin_amdgcn_s_setprio(1);
    bfrag af[2], bf[4];
#pragma unroll
    for (int mt = 0; mt < 2; ++mt) af[mt] = *(const bfrag*)(AlB + aoffs[mt]);
#pragma unroll
    for (int nt = 0; nt < 4; ++nt) bf[nt] = *(const bfrag*)(BlB + boffs[nt]);
#pragma unroll
    for (int mt = 0; mt < 2; ++mt)
#pragma unroll
      for (int nt = 0; nt < 4; ++nt)
        acc[mt][nt] = __builtin_amdgcn_mfma_f32_16x16x32_bf16(af[mt], bf[nt],
                                                              acc[mt][nt], 0, 0, 0);
    __builtin_amdgcn_s_setprio(0);
    CFENCE();
    SBAR();
    CFENCE();
  }
#pragma unroll
  for (int mt = 0; mt < 2; ++mt) {
#pragma unroll
    for (int nt = 0; nt < 4; ++nt) {
#pragma unroll
      for (int r = 0; r < 4; ++r) {
        int row = m0 + wm * 32 + mt * 16 + l4 * 4 + r;
        int col = n0 + wn * 64 + nt * 16 + l15;
        float v = acc[mt][nt][r];
        if (col < HIDDEN) {
          Qb[(size_t)row * HIDDEN + col] = f2bf(v + bq[col] * SCALE_L2E);
        } else if (col < HIDDEN + HDIM) {
          int lc = col - HIDDEN;
          Kb[(size_t)row * HDIM + lc] = f2bf(v + bk[lc]);
        } else {
          int lc = col - HIDDEN - HDIM;
          Vtb[(size_t)lc * M + pv_perm64(row)] = f2bf(v + bv[lc]);
        }
      }
    }
  }
}

// ---------------------------------------------------------------------------
// gemm_out: BK=64 8-wave dbuf pipeline. Grid (32, 16).
#define GEMM_STAGE8(buf, kt)                                                   \
  _Pragma("unroll") for (int it_ = 0; it_ < 2; ++it_) {                        \
    gl_lds16(ap[it_] + (kt) * 64, &Al[buf][(w * 2 + it_) * 512]);              \
    gl_lds16(bp[it_] + (kt) * 64, &Bl[buf][(w * 2 + it_) * 512]);              \
  }

__global__ __launch_bounds__(512, 4) void gemm_out(const short* __restrict__ A,
                                                   const short* __restrict__ BT,
                                                   const float* __restrict__ bias,
                                                   float* __restrict__ Cout,
                                                   int M, int N, int K) {
  __shared__ __align__(16) short Al[2][128 * 64];
  __shared__ __align__(16) short Bl[2][128 * 64];
  const int tid = threadIdx.x;
  const int w = tid >> 6, l = tid & 63;
  const int wm = w >> 1, wn = w & 1;
  const int l15 = l & 15, l4 = l >> 4;
  const int m0 = blockIdx.x * 128, n0 = blockIdx.y * 128;
  facc acc[2][4] = {};
  const int nkt = K >> 6;
  const short *ap[2], *bp[2];
#pragma unroll
  for (int it_ = 0; it_ < 2; ++it_) {
    int C = (w * 2 + it_) * 64 + l;
    int row = C >> 3, c = C & 7;
    int sz = (c ^ (row & 7)) << 3;
    ap[it_] = A + (size_t)(m0 + row) * K + sz;
    bp[it_] = BT + (size_t)(n0 + row) * K + sz;
  }
  int aoffs[2][2], boffs[2][4];
#pragma unroll
  for (int ks = 0; ks < 2; ++ks) {
#pragma unroll
    for (int mt = 0; mt < 2; ++mt) {
      int row = wm * 32 + mt * 16 + l15, c = ks * 4 + l4;
      aoffs[ks][mt] = row * 128 + ((c ^ (row & 7)) << 4);
    }
#pragma unroll
    for (int nt = 0; nt < 4; ++nt) {
      int row = wn * 64 + nt * 16 + l15, c = ks * 4 + l4;
      boffs[ks][nt] = row * 128 + ((c ^ (row & 7)) << 4);
    }
  }
  GEMM_STAGE8(0, 0)
  for (int kt = 0; kt < nkt; ++kt) {
    const int cur = kt & 1;
    if (kt + 1 < nkt) {
      GEMM_STAGE8(cur ^ 1, kt + 1)
      WAIT_VM(4);
    } else {
      WAIT_VM(0);
    }
    SBAR();
    CFENCE();
    const char* AlB = (const char*)Al + (cur << 14);
    const char* BlB = (const char*)Bl + (cur << 14);
    __builtin_amdgcn_s_setprio(1);
#pragma unroll
    for (int ks = 0; ks < 2; ++ks) {
      bfrag af[2], bf[4];
#pragma unroll
      for (int mt = 0; mt < 2; ++mt) af[mt] = *(const bfrag*)(AlB + aoffs[ks][mt]);
#pragma unroll
      for (int nt = 0; nt < 4; ++nt) bf[nt] = *(const bfrag*)(BlB + boffs[ks][nt]);
#pragma unroll
      for (int mt = 0; mt < 2; ++mt)
#pragma unroll
        for (int nt = 0; nt < 4; ++nt)
          acc[mt][nt] = __builtin_amdgcn_mfma_f32_16x16x32_bf16(af[mt], bf[nt],
                                                                acc[mt][nt], 0, 0, 0);
    }
    __builtin_amdgcn_s_setprio(0);
    CFENCE();
    SBAR();
    CFENCE();
  }
#pragma unroll
  for (int mt = 0; mt < 2; ++mt)
#pragma unroll
    for (int nt = 0; nt < 4; ++nt)
#pragma unroll
      for (int r = 0; r < 4; ++r) {
        int row = m0 + wm * 32 + mt * 16 + l4 * 4 + r;
        int col = n0 + wn * 64 + nt * 16 + l15;
        Cout[(size_t)row * N + col] = acc[mt][nt][r] + bias[col];
      }
}

// ---------------------------------------------------------------------------
// Flash attention: swapped QK^T, causal-paired blocks, 4 waves x 16 q-rows.
// Grid: (16, HEADS, B) = 512 blocks, 256 threads, 32KB LDS (K only, dbuf) ->
// 2 blocks/CU. V read DIRECTLY from global Vt (L2-resident; PV-permuted ->
// each lane's 8 PV keys are one contiguous 16B load). V loads issue at iter
// top (hide under QK^T); compiler inserts the precise vmcnt for the register
// dependence. Manual vmcnt(20/16) guards K staging: issue order per iter is
// [V:16, Kstage(t+1):4] after K(t):4 from prev iter -> vmcnt(20) retires K(t).
__global__ __launch_bounds__(256, 2) void attn_kernel(const short* __restrict__ Q,
                                                      const short* __restrict__ Kg,
                                                      const short* __restrict__ Vt,
                                                      unsigned short* __restrict__ O) {
  __shared__ __align__(16) short Kl[2][64 * 128];  // [buf][key][d] swizzled
  const int tid = threadIdx.x;
  const int w = tid >> 6, l = tid & 63;
  const int l15 = l & 15, l4 = l >> 4;
  const int h = blockIdx.y, b = blockIdx.z;

  // per-lane K global stage offsets (elements; loop-invariant)
  int kgo[4];
#pragma unroll
  for (int it = 0; it < 4; ++it) {
    int C = (w * 4 + it) * 64 + l;
    int key = C >> 4, ck = C & 15;
    kgo[it] = key * HDIM + ((ck ^ (key & 7)) << 3);
  }
  // per-lane K LDS read byte offsets (buffer 0; loop-invariant)
  int koffs[16];
#pragma unroll
  for (int kk = 0; kk < 4; ++kk)
#pragma unroll
    for (int kt = 0; kt < 4; ++kt) {
      int key = kt * 16 + l15, c = kk * 4 + l4;
      koffs[kk * 4 + kt] = key * 256 + ((c ^ (key & 7)) << 4);
    }
  // per-lane V global offsets (elements; +kv0 per tile). Pre-permuted Vt:
  // bv[c*8+nt] keys live at pos kv0 + c*32 + l4*8 of row d = nt*16+l15.
  int vbo[16];
#pragma unroll
  for (int c = 0; c < 2; ++c)
#pragma unroll
    for (int nt = 0; nt < 8; ++nt) {
      int d = nt * 16 + l15;
      vbo[c * 8 + nt] = d * (BATCH * SEQ) + c * 32 + l4 * 8;
    }
  const short* kg0 = Kg + (size_t)b * SEQ * HDIM;
  const short* vg0 = Vt + (size_t)b * SEQ;

#define STAGE_K(buf, t)                                                        \
  do {                                                                         \
    const short* kgp = kg0 + (size_t)(t) * (64 * HDIM);                        \
    _Pragma("unroll") for (int it = 0; it < 4; ++it)                           \
        gl_lds16(kgp + kgo[it], &Kl[buf][(w * 4 + it) * 512]);                 \
  } while (0)

  for (int pass = 0; pass < 2; ++pass) {
    const int qtile = (pass == 0) ? (int)blockIdx.x : 31 - (int)blockIdx.x;
    const int q0 = qtile * 64;
    const int qw = q0 + w * 16;  // this wave's 16 q-rows [qw, qw+16)

    // Q fragments (B-operand: col=q=l15, k contiguous): 4 k-chunks of 32
    bfrag aq[4];
#pragma unroll
    for (int kk = 0; kk < 4; ++kk)
      aq[kk] = *(const bfrag*)(Q + (size_t)(b * SEQ + qw + l15) * HIDDEN +
                               h * HDIM + kk * 32 + l4 * 8);

    facc accO[8] = {};
    float mrow = -INFINITY, lrow = 0.f;
    const int nkv = qtile + 1;

    STAGE_K(0, 0);

    for (int t = 0; t < nkv; ++t) {
      const int cur = t & 1;
      const int kv0 = t << 6;

      // V fragments direct from global (L2): 16 x 16B, issued early.
      const short* vp = vg0 + kv0;
      bfrag bv[16];
#pragma unroll
      for (int i = 0; i < 16; ++i)
        bv[i] = *(const bfrag*)(vp + vbo[i]);
      CFENCE();

      if (t + 1 < nkv) {
        STAGE_K(cur ^ 1, t + 1);
        WAIT_VM(20);  // retire K(t):4 (oldest); V:16 + K(t+1):4 stay in flight
      } else {
        WAIT_VM(16);  // retire K(t):4; V:16 in flight
      }
      SBAR();
      CFENCE();
      const char* KlB = (const char*)Kl + (cur << 14);

      // S^T = K * Q^T : A-frag = K (row=key=l15), B-frag = Q (col=q=l15).
      facc sac[4] = {};
      __builtin_amdgcn_s_setprio(1);
#pragma unroll
      for (int kk = 0; kk < 4; ++kk) {
#pragma unroll
        for (int kt = 0; kt < 4; ++kt) {
          bfrag ak = *(const bfrag*)(KlB + koffs[kk * 4 + kt]);
          sac[kt] = __builtin_amdgcn_mfma_f32_16x16x32_bf16(ak, aq[kk], sac[kt], 0, 0, 0);
        }
      }
      __builtin_amdgcn_s_setprio(0);
      CFENCE();
      SBAR();  // all waves done reading Kl[cur]; next iter may overwrite
      CFENCE();

      // ---- register-only tail: softmax + PV ----
      const int qg = qw + l15;
      const bool needmask = (kv0 + 63 > qw);
      float p[4][4];
#pragma unroll
      for (int kt = 0; kt < 4; ++kt)
#pragma unroll
        for (int r = 0; r < 4; ++r) {
          float v = sac[kt][r];
          if (needmask) {
            int keyg = kv0 + kt * 16 + l4 * 4 + r;
            v = (keyg <= qg) ? v : -INFINITY;
          }
          p[kt][r] = v;
        }
      // tree max (depth 4)
      float m0_ = fmaxf(fmaxf(p[0][0], p[0][1]), fmaxf(p[0][2], p[0][3]));
      float m1_ = fmaxf(fmaxf(p[1][0], p[1][1]), fmaxf(p[1][2], p[1][3]));
      float m2_ = fmaxf(fmaxf(p[2][0], p[2][1]), fmaxf(p[2][2], p[2][3]));
      float m3_ = fmaxf(fmaxf(p[3][0], p[3][1]), fmaxf(p[3][2], p[3][3]));
      float mt = fmaxf(fmaxf(m0_, m1_), fmaxf(m2_, m3_));
      mt = fmaxf(mt, __shfl_xor(mt, 16));
      mt = fmaxf(mt, __shfl_xor(mt, 32));
      // defer-max: rescale only when the running max grew by > 8 (log2)
      if (!__all(mt <= mrow + 8.0f)) {
        float mn = fmaxf(mrow, mt);
        float f = exp2f(mrow - mn);
        mrow = mn;
        lrow *= f;
        float fr[4];
#pragma unroll
        for (int r = 0; r < 4; ++r) fr[r] = __shfl(f, l4 * 4 + r);
#pragma unroll
        for (int nt = 0; nt < 8; ++nt)
#pragma unroll
          for (int r = 0; r < 4; ++r) accO[nt][r] *= fr[r];
      }
#pragma unroll
      for (int kt = 0; kt < 4; ++kt)
#pragma unroll
        for (int r = 0; r < 4; ++r) p[kt][r] = exp2f(p[kt][r] - mrow);
      // tree sum (depth 4)
      float s0_ = (p[0][0] + p[0][1]) + (p[0][2] + p[0][3]);
      float s1_ = (p[1][0] + p[1][1]) + (p[1][2] + p[1][3]);
      float s2_ = (p[2][0] + p[2][1]) + (p[2][2] + p[2][3]);
      float s3_ = (p[3][0] + p[3][1]) + (p[3][2] + p[3][3]);
      float ps = (s0_ + s1_) + (s2_ + s3_);
      ps += __shfl_xor(ps, 16);
      ps += __shfl_xor(ps, 32);
      lrow += ps;

      // PV (zero-shuffle): pa built in-register via bit_cast (TBAA-safe).
      // pa slots g*8+{0..3} = p[2c][0..3], {4..7} = p[2c+1][0..3].
      __builtin_amdgcn_s_setprio(1);
#pragma unroll
      for (int c = 0; c < 2; ++c) {
        uifrag up;
        up.x = cvt_pk_bf16(p[2 * c][0], p[2 * c][1]);
        up.y = cvt_pk_bf16(p[2 * c][2], p[2 * c][3]);
        up.z = cvt_pk_bf16(p[2 * c + 1][0], p[2 * c + 1][1]);
        up.w = cvt_pk_bf16(p[2 * c + 1][2], p[2 * c + 1][3]);
        bfrag pa = __builtin_bit_cast(bfrag, up);
#pragma unroll
        for (int nt = 0; nt < 8; ++nt)
          accO[nt] = __builtin_amdgcn_mfma_f32_16x16x32_bf16(pa, bv[c * 8 + nt],
                                                             accO[nt], 0, 0, 0);
      }
      __builtin_amdgcn_s_setprio(0);
    }

    // epilogue: O rows q = l4*4+r, cols d = nt*16+l15
    float inv = 1.f / lrow;
#pragma unroll
    for (int r = 0; r < 4; ++r) {
      float invr = __shfl(inv, l4 * 4 + r);
      int row = qw + l4 * 4 + r;
#pragma unroll
      for (int nt = 0; nt < 8; ++nt)
        O[(size_t)(b * SEQ + row) * HIDDEN + h * HDIM + nt * 16 + l15] =
            f2bf(accO[nt][r] * invr);
    }
  }
#undef STAGE_K
}

// ---------------------------------------------------------------------------
extern "C" void kernel_launch(void* const* d_in, const int* in_sizes, int n_in,
                              void* d_out, int out_size, void* d_ws, size_t ws_size,
                              hipStream_t stream) {
  const float* x = (const float*)d_in[0];
  // d_in[1] = mask (causal, applied analytically)
  const float* Wq = (const float*)d_in[2];
  const float* bq = (const float*)d_in[3];
  const float* Wk = (const float*)d_in[4];
  const float* bk = (const float*)d_in[5];
  const float* Wv = (const float*)d_in[6];
  const float* bv = (const float*)d_in[7];
  const float* Wo = (const float*)d_in[8];
  const float* bo = (const float*)d_in[9];
  float* out = (float*)d_out;

  const size_t MS = (size_t)BATCH * SEQ;  // 4096
  char* ws = (char*)d_ws;
  short* xb = (short*)ws;      ws += MS * HIDDEN * 2;
  short* WqkvT = (short*)ws;   ws += (size_t)(HIDDEN + 2 * HDIM) * HIDDEN * 2;  // 2304 rows
  short* WoT = (short*)ws;     ws += (size_t)HIDDEN * HIDDEN * 2;
  short* Qb = (short*)ws;      ws += MS * HIDDEN * 2;
  short* Kb = (short*)ws;      ws += MS * HDIM * 2;
  short* Vtb = (short*)ws;     ws += (size_t)HDIM * MS * 2;
  short* Ab = (short*)ws;      ws += MS * HIDDEN * 2;

  cvt_bf16<<<(int)(MS * HIDDEN / 4 / 256), 256, 0, stream>>>(
      x, (unsigned int*)xb, (int)(MS * HIDDEN / 4));
  transpose_cvt2<<<dim3(HIDDEN / 32, HIDDEN / 32, 2), 256, 0, stream>>>(
      Wq, WqkvT, Wo, WoT, HIDDEN, HIDDEN, SCALE_L2E, 1.0f);
  transpose_cvt2<<<dim3(HDIM / 32, HIDDEN / 32, 2), 256, 0, stream>>>(
      Wk, WqkvT + (size_t)HIDDEN * HIDDEN, Wv, WqkvT + (size_t)(HIDDEN + HDIM) * HIDDEN,
      HIDDEN, HDIM, 1.0f, 1.0f);

  gemm_qkv<<<dim3(32, 18), 512, 0, stream>>>(xb, WqkvT, bq, bk, bv,
                                             (unsigned short*)Qb, (unsigned short*)Kb,
                                             (unsigned short*)Vtb, (int)MS, HIDDEN);

  attn_kernel<<<dim3(16, NHEADS, BATCH), 256, 0, stream>>>(Qb, Kb, Vtb,
                                                           (unsigned short*)Ab);

  gemm_out<<<dim3(32, 16), 512, 0, stream>>>(Ab, WoT, bo, out, (int)MS, HIDDEN, HIDDEN);
}

// Round 17
// 184.942 us; speedup vs baseline: 1.3647x; 1.3647x over previous
//
#include <hip/hip_runtime.h>

// ---------------------------------------------------------------------------
// MultiQueryAttention: out = softmax_causal((xWq+bq)(xWk+bk)^T * scale) (xWv+bv) Wo + bo
// B=2, S=2048, HIDDEN=2048, HEADS=16 (multi-query: 1 KV head), HEAD_DIM=128
// R16: attn REVERTED to R14 (best: V staged in LDS; R15's direct-L2 V read
//      quadrupled per-block L2 traffic and exposed L2 latency -> 142us).
//      Preamble fused: ONE prep kernel (4 weight transposes + x cvt) replaces
//      3 launches. GEMMs unchanged (R14: qkv BK=32, out BK=64).
// ---------------------------------------------------------------------------

#define HIDDEN 2048
#define NHEADS 16
#define HDIM 128
#define BATCH 2
#define SEQ 2048
// SCALE_QK * log2(e): softmax computed in base-2 (exp2); folded into Wq/bq.
#define SCALE_L2E 0.1275258653864023f

typedef __attribute__((ext_vector_type(8))) short bfrag;   // 8 bf16 (4 VGPRs)
typedef __attribute__((ext_vector_type(4))) float facc;    // MFMA accumulator
typedef __attribute__((ext_vector_type(4))) unsigned int uifrag;  // 4 u32 = 8 bf16

__device__ __forceinline__ unsigned short f2bf(float f) {  // f32 -> bf16 RNE
  unsigned int u = __float_as_uint(f);
  u += 0x7fffu + ((u >> 16) & 1u);
  return (unsigned short)(u >> 16);
}

// HW packed f32x2 -> bf16x2 (RNE); no builtin on gfx950, inline asm (T12).
__device__ __forceinline__ unsigned int cvt_pk_bf16(float lo, float hi) {
  unsigned int r;
  asm("v_cvt_pk_bf16_f32 %0, %1, %2" : "=v"(r) : "v"(lo), "v"(hi));
  return r;
}

// async global->LDS, 16B per lane. LDS dest is WAVE-UNIFORM base (+lane*16 by HW).
__device__ __forceinline__ void gl_lds16(const void* g, void* l) {
  __builtin_amdgcn_global_load_lds(
      (const __attribute__((address_space(1))) void*)g,
      (__attribute__((address_space(3))) void*)l, 16, 0, 0);
}

#define SBAR() __builtin_amdgcn_s_barrier()
#define CFENCE() asm volatile("" ::: "memory")
#define WAIT_VM(n) asm volatile("s_waitcnt vmcnt(" #n ")" ::: "memory")

// ---------------------------------------------------------------------------
// Fused preamble: grid (68, 64, 3), 256 threads.
//  z==2           : grid-stride f32->bf16 cvt of x (n4 float4 elements)
//  z==0, x<64     : Wq -> WqkvT rows [0,2048)        (scaled by SCALE_L2E)
//  z==0, x>=64    : Wk -> WqkvT rows [2048,2176)
//  z==1, x<64     : Wo -> WoT
//  z==1, x>=64    : Wv -> WqkvT rows [2176,2304)
__global__ __launch_bounds__(256) void prep(const float* __restrict__ x,
                                            unsigned int* __restrict__ xb4,
                                            const float* __restrict__ Wq,
                                            const float* __restrict__ Wk,
                                            const float* __restrict__ Wv,
                                            const float* __restrict__ Wo,
                                            short* __restrict__ WqkvT,
                                            short* __restrict__ WoT, int n4) {
  if (blockIdx.z == 2) {
    int stride = gridDim.x * gridDim.y * 256;
    int i = ((int)blockIdx.y * gridDim.x + blockIdx.x) * 256 + threadIdx.x;
    for (; i < n4; i += stride) {
      float4 v = ((const float4*)x)[i];
      uint2 o = {cvt_pk_bf16(v.x, v.y), cvt_pk_bf16(v.z, v.w)};
      ((uint2*)xb4)[i] = o;
    }
    return;
  }
  const float* W;
  short* WT;
  int N;
  float s;
  int bx = blockIdx.x;
  if (blockIdx.z == 0) {
    if (bx < 64) { W = Wq; WT = WqkvT; N = HIDDEN; s = SCALE_L2E; }
    else { W = Wk; WT = WqkvT + (size_t)HIDDEN * HIDDEN; N = HDIM; s = 1.f; bx -= 64; }
  } else {
    if (bx < 64) { W = Wo; WT = WoT; N = HIDDEN; s = 1.f; }
    else { W = Wv; WT = WqkvT + (size_t)(HIDDEN + HDIM) * HIDDEN; N = HDIM; s = 1.f; bx -= 64; }
  }
  __shared__ float t[32][33];
  int tx = threadIdx.x & 31, ty = threadIdx.x >> 5;
  int n0 = bx * 32, k0 = blockIdx.y * 32;
#pragma unroll
  for (int j = 0; j < 4; ++j)
    t[ty + j * 8][tx] = W[(size_t)(k0 + ty + j * 8) * N + n0 + tx];
  __syncthreads();
#pragma unroll
  for (int j = 0; j < 4; ++j)
    WT[(size_t)(n0 + ty + j * 8) * HIDDEN + k0 + tx] = (short)f2bf(t[tx][ty + j * 8] * s);
}

// PV-order permutation of a key index within its 64-block:
// key bits [c][h][g1g0][r1r0] -> pos bits [c][g1g0][h][r1r0].
__device__ __forceinline__ int pv_perm64(int row) {
  int k = row & 63;
  int p = (k & 0x23) | ((k & 0x0C) << 1) | ((k & 0x10) >> 2);
  return (row & ~63) | p;
}

// ---------------------------------------------------------------------------
// gemm_qkv: BK=32 pipeline. 512 threads = 8 waves (4M x 2N), per-wave C 32x64.
// LDS 32KB -> 3 blocks/CU; grid 576 fully resident. Grid (32, 18).
__global__ __launch_bounds__(512, 6) void gemm_qkv(const short* __restrict__ A,
                                                   const short* __restrict__ BT,
                                                   const float* __restrict__ bq,
                                                   const float* __restrict__ bk,
                                                   const float* __restrict__ bv,
                                                   unsigned short* __restrict__ Qb,
                                                   unsigned short* __restrict__ Kb,
                                                   unsigned short* __restrict__ Vtb,
                                                   int M, int K) {
  __shared__ __align__(16) short Al[2][128 * 32];
  __shared__ __align__(16) short Bl[2][128 * 32];
  const int tid = threadIdx.x;
  const int w = tid >> 6, l = tid & 63;
  const int wm = w >> 1, wn = w & 1;
  const int l15 = l & 15, l4 = l >> 4;
  const int m0 = blockIdx.x * 128, n0 = blockIdx.y * 128;

  const short *ap, *bp;
  {
    int C = w * 64 + l;
    int row = C >> 2, c = C & 3;
    int sz = (c ^ (row & 3)) << 3;
    ap = A + (size_t)(m0 + row) * K + sz;
    bp = BT + (size_t)(n0 + row) * K + sz;
  }
  int aoffs[2], boffs[4];
#pragma unroll
  for (int mt = 0; mt < 2; ++mt) {
    int row = wm * 32 + mt * 16 + l15;
    aoffs[mt] = row * 64 + ((l4 ^ (row & 3)) << 4);
  }
#pragma unroll
  for (int nt = 0; nt < 4; ++nt) {
    int row = wn * 64 + nt * 16 + l15;
    boffs[nt] = row * 64 + ((l4 ^ (row & 3)) << 4);
  }

  facc acc[2][4] = {};
  const int nkt = K >> 5;  // 64
  gl_lds16(ap, &Al[0][w * 512]);
  gl_lds16(bp, &Bl[0][w * 512]);
  for (int kt = 0; kt < nkt; ++kt) {
    const int cur = kt & 1;
    if (kt + 1 < nkt) {
      gl_lds16(ap + (kt + 1) * 32, &Al[cur ^ 1][w * 512]);
      gl_lds16(bp + (kt + 1) * 32, &Bl[cur ^ 1][w * 512]);
      WAIT_VM(2);
    } else {
      WAIT_VM(0);
    }
    SBAR();
    CFENCE();
    const char* AlB = (const char*)Al + (cur << 13);
    const char* BlB = (const char*)Bl + (cur << 13);
    __builtin_amdgcn_s_setprio(1);
    bfrag af[2], bf[4];
#pragma unroll
    for (int mt = 0; mt < 2; ++mt) af[mt] = *(const bfrag*)(AlB + aoffs[mt]);
#pragma unroll
    for (int nt = 0; nt < 4; ++nt) bf[nt] = *(const bfrag*)(BlB + boffs[nt]);
#pragma unroll
    for (int mt = 0; mt < 2; ++mt)
#pragma unroll
      for (int nt = 0; nt < 4; ++nt)
        acc[mt][nt] = __builtin_amdgcn_mfma_f32_16x16x32_bf16(af[mt], bf[nt],
                                                              acc[mt][nt], 0, 0, 0);
    __builtin_amdgcn_s_setprio(0);
    CFENCE();
    SBAR();
    CFENCE();
  }
#pragma unroll
  for (int mt = 0; mt < 2; ++mt) {
#pragma unroll
    for (int nt = 0; nt < 4; ++nt) {
#pragma unroll
      for (int r = 0; r < 4; ++r) {
        int row = m0 + wm * 32 + mt * 16 + l4 * 4 + r;
        int col = n0 + wn * 64 + nt * 16 + l15;
        float v = acc[mt][nt][r];
        if (col < HIDDEN) {
          Qb[(size_t)row * HIDDEN + col] = f2bf(v + bq[col] * SCALE_L2E);
        } else if (col < HIDDEN + HDIM) {
          int lc = col - HIDDEN;
          Kb[(size_t)row * HDIM + lc] = f2bf(v + bk[lc]);
        } else {
          int lc = col - HIDDEN - HDIM;
          Vtb[(size_t)lc * M + pv_perm64(row)] = f2bf(v + bv[lc]);
        }
      }
    }
  }
}

// ---------------------------------------------------------------------------
// gemm_out: BK=64 8-wave dbuf pipeline. Grid (32, 16).
#define GEMM_STAGE8(buf, kt)                                                   \
  _Pragma("unroll") for (int it_ = 0; it_ < 2; ++it_) {                        \
    gl_lds16(ap[it_] + (kt) * 64, &Al[buf][(w * 2 + it_) * 512]);              \
    gl_lds16(bp[it_] + (kt) * 64, &Bl[buf][(w * 2 + it_) * 512]);              \
  }

__global__ __launch_bounds__(512, 4) void gemm_out(const short* __restrict__ A,
                                                   const short* __restrict__ BT,
                                                   const float* __restrict__ bias,
                                                   float* __restrict__ Cout,
                                                   int M, int N, int K) {
  __shared__ __align__(16) short Al[2][128 * 64];
  __shared__ __align__(16) short Bl[2][128 * 64];
  const int tid = threadIdx.x;
  const int w = tid >> 6, l = tid & 63;
  const int wm = w >> 1, wn = w & 1;
  const int l15 = l & 15, l4 = l >> 4;
  const int m0 = blockIdx.x * 128, n0 = blockIdx.y * 128;
  facc acc[2][4] = {};
  const int nkt = K >> 6;
  const short *ap[2], *bp[2];
#pragma unroll
  for (int it_ = 0; it_ < 2; ++it_) {
    int C = (w * 2 + it_) * 64 + l;
    int row = C >> 3, c = C & 7;
    int sz = (c ^ (row & 7)) << 3;
    ap[it_] = A + (size_t)(m0 + row) * K + sz;
    bp[it_] = BT + (size_t)(n0 + row) * K + sz;
  }
  int aoffs[2][2], boffs[2][4];
#pragma unroll
  for (int ks = 0; ks < 2; ++ks) {
#pragma unroll
    for (int mt = 0; mt < 2; ++mt) {
      int row = wm * 32 + mt * 16 + l15, c = ks * 4 + l4;
      aoffs[ks][mt] = row * 128 + ((c ^ (row & 7)) << 4);
    }
#pragma unroll
    for (int nt = 0; nt < 4; ++nt) {
      int row = wn * 64 + nt * 16 + l15, c = ks * 4 + l4;
      boffs[ks][nt] = row * 128 + ((c ^ (row & 7)) << 4);
    }
  }
  GEMM_STAGE8(0, 0)
  for (int kt = 0; kt < nkt; ++kt) {
    const int cur = kt & 1;
    if (kt + 1 < nkt) {
      GEMM_STAGE8(cur ^ 1, kt + 1)
      WAIT_VM(4);
    } else {
      WAIT_VM(0);
    }
    SBAR();
    CFENCE();
    const char* AlB = (const char*)Al + (cur << 14);
    const char* BlB = (const char*)Bl + (cur << 14);
    __builtin_amdgcn_s_setprio(1);
#pragma unroll
    for (int ks = 0; ks < 2; ++ks) {
      bfrag af[2], bf[4];
#pragma unroll
      for (int mt = 0; mt < 2; ++mt) af[mt] = *(const bfrag*)(AlB + aoffs[ks][mt]);
#pragma unroll
      for (int nt = 0; nt < 4; ++nt) bf[nt] = *(const bfrag*)(BlB + boffs[ks][nt]);
#pragma unroll
      for (int mt = 0; mt < 2; ++mt)
#pragma unroll
        for (int nt = 0; nt < 4; ++nt)
          acc[mt][nt] = __builtin_amdgcn_mfma_f32_16x16x32_bf16(af[mt], bf[nt],
                                                                acc[mt][nt], 0, 0, 0);
    }
    __builtin_amdgcn_s_setprio(0);
    CFENCE();
    SBAR();
    CFENCE();
  }
#pragma unroll
  for (int mt = 0; mt < 2; ++mt)
#pragma unroll
    for (int nt = 0; nt < 4; ++nt)
#pragma unroll
      for (int r = 0; r < 4; ++r) {
        int row = m0 + wm * 32 + mt * 16 + l4 * 4 + r;
        int col = n0 + wn * 64 + nt * 16 + l15;
        Cout[(size_t)row * N + col] = acc[mt][nt][r] + bias[col];
      }
}

// ---------------------------------------------------------------------------
// Flash attention (R14 config): swapped QK^T, causal-paired blocks, 4 waves x
// 16 q-rows. Grid: (16, HEADS, B) = 512 blocks, 256 threads, 64KB LDS ->
// 2 blocks/CU. Hoisted addressing; counted-vmcnt pipeline; zero-shuffle PV
// with pre-permuted Vt; tree max/sum; defer-max.
__global__ __launch_bounds__(256, 2) void attn_kernel(const short* __restrict__ Q,
                                                      const short* __restrict__ Kg,
                                                      const short* __restrict__ Vt,
                                                      unsigned short* __restrict__ O) {
  __shared__ __align__(16) short Kl[2][64 * 128];  // [buf][key][d] swizzled
  __shared__ __align__(16) short Vl[2][128 * 64];  // [buf][d][pos] swizzled
  const int tid = threadIdx.x;
  const int w = tid >> 6, l = tid & 63;
  const int l15 = l & 15, l4 = l >> 4;
  const int h = blockIdx.y, b = blockIdx.z;

  // per-lane global stage offsets (elements; loop-invariant)
  int kgo[4], vgo[4];
#pragma unroll
  for (int it = 0; it < 4; ++it) {
    int C = (w * 4 + it) * 64 + l;
    int key = C >> 4, ck = C & 15;
    kgo[it] = key * HDIM + ((ck ^ (key & 7)) << 3);
    int d = C >> 3, cv = C & 7;
    vgo[it] = d * (BATCH * SEQ) + ((cv ^ (d & 7)) << 3);
  }
  // per-lane LDS read byte offsets (buffer 0; loop-invariant)
  int koffs[16], voffs[16];
#pragma unroll
  for (int kk = 0; kk < 4; ++kk)
#pragma unroll
    for (int kt = 0; kt < 4; ++kt) {
      int key = kt * 16 + l15, c = kk * 4 + l4;
      koffs[kk * 4 + kt] = key * 256 + ((c ^ (key & 7)) << 4);
    }
#pragma unroll
  for (int c = 0; c < 2; ++c)
#pragma unroll
    for (int nt = 0; nt < 8; ++nt) {
      int d = nt * 16 + l15, cc = c * 4 + l4;
      voffs[c * 8 + nt] = d * 128 + ((cc ^ (d & 7)) << 4);
    }
  const short* kg0 = Kg + (size_t)b * SEQ * HDIM;
  const short* vg0 = Vt + (size_t)b * SEQ;

#define STAGE_KV(buf, t)                                                       \
  do {                                                                         \
    const short* kgp = kg0 + (size_t)(t) * (64 * HDIM);                        \
    const short* vgp = vg0 + (size_t)(t) * 64;                                 \
    _Pragma("unroll") for (int it = 0; it < 4; ++it)                           \
        gl_lds16(kgp + kgo[it], &Kl[buf][(w * 4 + it) * 512]);                 \
    _Pragma("unroll") for (int it = 0; it < 4; ++it)                           \
        gl_lds16(vgp + vgo[it], &Vl[buf][(w * 4 + it) * 512]);                 \
  } while (0)

  for (int pass = 0; pass < 2; ++pass) {
    const int qtile = (pass == 0) ? (int)blockIdx.x : 31 - (int)blockIdx.x;
    const int q0 = qtile * 64;
    const int qw = q0 + w * 16;  // this wave's 16 q-rows [qw, qw+16)

    // Q fragments (B-operand: col=q=l15, k contiguous): 4 k-chunks of 32
    bfrag aq[4];
#pragma unroll
    for (int kk = 0; kk < 4; ++kk)
      aq[kk] = *(const bfrag*)(Q + (size_t)(b * SEQ + qw + l15) * HIDDEN +
                               h * HDIM + kk * 32 + l4 * 8);

    facc accO[8] = {};
    float mrow = -INFINITY, lrow = 0.f;
    const int nkv = qtile + 1;

    STAGE_KV(0, 0);

    for (int t = 0; t < nkv; ++t) {
      const int cur = t & 1;
      if (t + 1 < nkv) {
        STAGE_KV(cur ^ 1, t + 1);
        WAIT_VM(8);  // tile t's 8 loads landed; t+1's stay in flight
      } else {
        WAIT_VM(0);
      }
      SBAR();
      CFENCE();
      const int kv0 = t << 6;
      const char* KlB = (const char*)Kl + (cur << 14);
      const char* VlB = (const char*)Vl + (cur << 14);

      // S^T = K * Q^T : A-frag = K (row=key=l15), B-frag = Q (col=q=l15).
      facc sac[4] = {};
      __builtin_amdgcn_s_setprio(1);
#pragma unroll
      for (int kk = 0; kk < 4; ++kk) {
#pragma unroll
        for (int kt = 0; kt < 4; ++kt) {
          bfrag ak = *(const bfrag*)(KlB + koffs[kk * 4 + kt]);
          sac[kt] = __builtin_amdgcn_mfma_f32_16x16x32_bf16(ak, aq[kk], sac[kt], 0, 0, 0);
        }
      }
      __builtin_amdgcn_s_setprio(0);

      // V fragment prefetch: one b128 per (c,nt); pre-permuted Vt makes chunk
      // (4c+l4) hold this lane's 8 PV keys.
      bfrag bv[16];
#pragma unroll
      for (int i = 0; i < 16; ++i)
        bv[i] = *(const bfrag*)(VlB + voffs[i]);
      CFENCE();
      SBAR();  // all waves done reading buffer cur; next iter may overwrite
      CFENCE();

      // ---- register-only tail: softmax + PV ----
      const int qg = qw + l15;
      const bool needmask = (kv0 + 63 > qw);
      float p[4][4];
#pragma unroll
      for (int kt = 0; kt < 4; ++kt)
#pragma unroll
        for (int r = 0; r < 4; ++r) {
          float v = sac[kt][r];
          if (needmask) {
            int keyg = kv0 + kt * 16 + l4 * 4 + r;
            v = (keyg <= qg) ? v : -INFINITY;
          }
          p[kt][r] = v;
        }
      // tree max (depth 4)
      float m0_ = fmaxf(fmaxf(p[0][0], p[0][1]), fmaxf(p[0][2], p[0][3]));
      float m1_ = fmaxf(fmaxf(p[1][0], p[1][1]), fmaxf(p[1][2], p[1][3]));
      float m2_ = fmaxf(fmaxf(p[2][0], p[2][1]), fmaxf(p[2][2], p[2][3]));
      float m3_ = fmaxf(fmaxf(p[3][0], p[3][1]), fmaxf(p[3][2], p[3][3]));
      float mt = fmaxf(fmaxf(m0_, m1_), fmaxf(m2_, m3_));
      mt = fmaxf(mt, __shfl_xor(mt, 16));
      mt = fmaxf(mt, __shfl_xor(mt, 32));
      // defer-max: rescale only when the running max grew by > 8 (log2)
      if (!__all(mt <= mrow + 8.0f)) {
        float mn = fmaxf(mrow, mt);
        float f = exp2f(mrow - mn);
        mrow = mn;
        lrow *= f;
        float fr[4];
#pragma unroll
        for (int r = 0; r < 4; ++r) fr[r] = __shfl(f, l4 * 4 + r);
#pragma unroll
        for (int nt = 0; nt < 8; ++nt)
#pragma unroll
          for (int r = 0; r < 4; ++r) accO[nt][r] *= fr[r];
      }
#pragma unroll
      for (int kt = 0; kt < 4; ++kt)
#pragma unroll
        for (int r = 0; r < 4; ++r) p[kt][r] = exp2f(p[kt][r] - mrow);
      // tree sum (depth 4)
      float s0_ = (p[0][0] + p[0][1]) + (p[0][2] + p[0][3]);
      float s1_ = (p[1][0] + p[1][1]) + (p[1][2] + p[1][3]);
      float s2_ = (p[2][0] + p[2][1]) + (p[2][2] + p[2][3]);
      float s3_ = (p[3][0] + p[3][1]) + (p[3][2] + p[3][3]);
      float ps = (s0_ + s1_) + (s2_ + s3_);
      ps += __shfl_xor(ps, 16);
      ps += __shfl_xor(ps, 32);
      lrow += ps;

      // PV (zero-shuffle): pa built in-register via bit_cast (TBAA-safe).
      // pa slots g*8+{0..3} = p[2c][0..3], {4..7} = p[2c+1][0..3].
      __builtin_amdgcn_s_setprio(1);
#pragma unroll
      for (int c = 0; c < 2; ++c) {
        uifrag up;
        up.x = cvt_pk_bf16(p[2 * c][0], p[2 * c][1]);
        up.y = cvt_pk_bf16(p[2 * c][2], p[2 * c][3]);
        up.z = cvt_pk_bf16(p[2 * c + 1][0], p[2 * c + 1][1]);
        up.w = cvt_pk_bf16(p[2 * c + 1][2], p[2 * c + 1][3]);
        bfrag pa = __builtin_bit_cast(bfrag, up);
#pragma unroll
        for (int nt = 0; nt < 8; ++nt)
          accO[nt] = __builtin_amdgcn_mfma_f32_16x16x32_bf16(pa, bv[c * 8 + nt],
                                                             accO[nt], 0, 0, 0);
      }
      __builtin_amdgcn_s_setprio(0);
    }

    // epilogue: O rows q = l4*4+r, cols d = nt*16+l15
    float inv = 1.f / lrow;
#pragma unroll
    for (int r = 0; r < 4; ++r) {
      float invr = __shfl(inv, l4 * 4 + r);
      int row = qw + l4 * 4 + r;
#pragma unroll
      for (int nt = 0; nt < 8; ++nt)
        O[(size_t)(b * SEQ + row) * HIDDEN + h * HDIM + nt * 16 + l15] =
            f2bf(accO[nt][r] * invr);
    }
  }
#undef STAGE_KV
}

// ---------------------------------------------------------------------------
extern "C" void kernel_launch(void* const* d_in, const int* in_sizes, int n_in,
                              void* d_out, int out_size, void* d_ws, size_t ws_size,
                              hipStream_t stream) {
  const float* x = (const float*)d_in[0];
  // d_in[1] = mask (causal, applied analytically)
  const float* Wq = (const float*)d_in[2];
  const float* bq = (const float*)d_in[3];
  const float* Wk = (const float*)d_in[4];
  const float* bk = (const float*)d_in[5];
  const float* Wv = (const float*)d_in[6];
  const float* bv = (const float*)d_in[7];
  const float* Wo = (const float*)d_in[8];
  const float* bo = (const float*)d_in[9];
  float* out = (float*)d_out;

  const size_t MS = (size_t)BATCH * SEQ;  // 4096
  char* ws = (char*)d_ws;
  short* xb = (short*)ws;      ws += MS * HIDDEN * 2;
  short* WqkvT = (short*)ws;   ws += (size_t)(HIDDEN + 2 * HDIM) * HIDDEN * 2;  // 2304 rows
  short* WoT = (short*)ws;     ws += (size_t)HIDDEN * HIDDEN * 2;
  short* Qb = (short*)ws;      ws += MS * HIDDEN * 2;
  short* Kb = (short*)ws;      ws += MS * HDIM * 2;
  short* Vtb = (short*)ws;     ws += (size_t)HDIM * MS * 2;
  short* Ab = (short*)ws;      ws += MS * HIDDEN * 2;

  prep<<<dim3(68, 64, 3), 256, 0, stream>>>(x, (unsigned int*)xb, Wq, Wk, Wv, Wo,
                                            WqkvT, WoT, (int)(MS * HIDDEN / 4));

  gemm_qkv<<<dim3(32, 18), 512, 0, stream>>>(xb, WqkvT, bq, bk, bv,
                                             (unsigned short*)Qb, (unsigned short*)Kb,
                                             (unsigned short*)Vtb, (int)MS, HIDDEN);

  attn_kernel<<<dim3(16, NHEADS, BATCH), 256, 0, stream>>>(Qb, Kb, Vtb,
                                                           (unsigned short*)Ab);

  gemm_out<<<dim3(32, 16), 512, 0, stream>>>(Ab, WoT, bo, out, (int)MS, HIDDEN, HIDDEN);
}